// Round 3
// baseline (238.951 us; speedup 1.0000x reference)
//
#include <hip/hip_runtime.h>
#include <hip/hip_cooperative_groups.h>

namespace cg = cooperative_groups;

#define B 64
#define N 1024
#define G 256
#define H 512
#define NBLK 1024
#define NTHR 256

// exp(-50*d^2) = 2^(-72.134752*d^2); pre-scale plane coeffs by sqrt(72.134752)
#define S_SCALE 8.4932183f
#define INV_S   (1.0f / S_SCALE)

__device__ __forceinline__ float exp2_fast(float x) {
#if __has_builtin(__builtin_amdgcn_exp2f)
    return __builtin_amdgcn_exp2f(x);   // raw v_exp_f32
#else
    return __expf(x * 0.69314718056f);  // e^(x ln2) = 2^x
#endif
}

union SMem {
    struct { float w[N]; int part[4][64]; } p1;           // 5.1 KB
    struct { float sp[3 * N]; float gp[3 * G]; } p2;      // 15.4 KB
    struct { float v[4]; int idx[4]; float sw[4]; float swl[4];
             float smax; int smaxi; } p3;                 // tiny
};

__global__ __launch_bounds__(NTHR, 4) void wdsac_kernel(
    const float* __restrict__ pts,        // (B,3,N)
    const float* __restrict__ target,     // (B,3)
    const float* __restrict__ pt_weight,  // (B,N)
    const int* __restrict__ sel_idx,      // (B,H,3)
    float* __restrict__ out,              // exp_loss|top_loss|pred|gpts
    float* __restrict__ score,            // ws (B,H)
    float* __restrict__ loss,             // ws (B,H)
    float* __restrict__ normals,          // ws (B,H,3)
    int* __restrict__ cnt,                // ws (B)
    int mode)                             // 0=fused(coop), 1=phase1 only, 2=phase2+3 only
{
    __shared__ SMem sm;
    __shared__ bool s_last;
    const int blk = blockIdx.x;
    const int tid = threadIdx.x;
    const int b   = blk >> 4;   // 64 batches
    const int hg  = blk & 15;   // 16 groups per batch
    const int wave = tid >> 6;
    const int lane = tid & 63;
    float* out_gpts = out + 5 * B;  // after exp_loss(B)+top_loss(B)+pred(3B)

    if (mode <= 1) {
        // ---------------- phase 1: stable top-k rank + gather ----------------
        // block (b,hg) ranks elements [64*hg, 64*hg+64); each thread covers a
        // 256-wide quarter of the j-loop for one element; LDS-reduce partials.
        ((float4*)sm.p1.w)[tid] = ((const float4*)(pt_weight + (size_t)b * N))[tid];
        if (tid == 0 && hg == 0) cnt[b] = 0;   // zero finalize counter each call
        __syncthreads();

        const int e = tid & 63;
        const int q = tid >> 6;            // j-quarter (wave-uniform)
        const int i = (hg << 6) + e;       // global element index
        const int Q = hg >> 2;             // quarter containing i (wave-uniform)
        const float wi = sm.p1.w[i];
        const float* wq = sm.p1.w + (q << 8);
        int r = 0;
        if (q < Q) {            // all j < i: ties count
            #pragma unroll 8
            for (int j = 0; j < 256; j += 4) {
                const float4 wj = *(const float4*)(wq + j);
                r += (wj.x >= wi) + (wj.y >= wi) + (wj.z >= wi) + (wj.w >= wi);
            }
        } else if (q > Q) {     // all j > i: ties don't count
            #pragma unroll 8
            for (int j = 0; j < 256; j += 4) {
                const float4 wj = *(const float4*)(wq + j);
                r += (wj.x > wi) + (wj.y > wi) + (wj.z > wi) + (wj.w > wi);
            }
        } else {                // mixed quarter
            const int j0 = q << 8;
            #pragma unroll 8
            for (int j = 0; j < 256; j += 4) {
                const float4 wj = *(const float4*)(wq + j);
                r += (wj.x > wi) || (wj.x == wi && (j0 + j + 0) < i);
                r += (wj.y > wi) || (wj.y == wi && (j0 + j + 1) < i);
                r += (wj.z > wi) || (wj.z == wi && (j0 + j + 2) < i);
                r += (wj.w > wi) || (wj.w == wi && (j0 + j + 3) < i);
            }
        }
        sm.p1.part[q][e] = r;
        __syncthreads();
        if (tid < 64) {
            const int rank = sm.p1.part[0][tid] + sm.p1.part[1][tid]
                           + sm.p1.part[2][tid] + sm.p1.part[3][tid];
            if (rank < G) {
                const int ii = (hg << 6) + tid;
                const size_t pb = (size_t)b * 3 * N;
                float* dst = out_gpts + ((size_t)b * G + rank) * 3;
                dst[0] = pts[pb + ii];
                dst[1] = pts[pb + N + ii];
                dst[2] = pts[pb + 2 * N + ii];
            }
        }
    }

    if (mode == 1) return;
    if (mode == 0) cg::this_grid().sync();

    // ---------------- phase 2: plane + score + loss ----------------
    {
        const float4* ps = (const float4*)(pts + (size_t)b * 3 * N);
        float4* spv = (float4*)sm.p2.sp;
        spv[tid]       = ps[tid];
        spv[tid + 256] = ps[tid + 256];
        spv[tid + 512] = ps[tid + 512];
        if (tid < 192)
            ((float4*)sm.p2.gp)[tid] =
                ((const float4*)(out_gpts + (size_t)b * 3 * G))[tid];
        __syncthreads();

        const int h0 = (hg << 5) + (wave << 3);  // 32 hyps/block, 8/wave
        float nx[8], ny[8], nz[8], pd[8], acc[8];

        #pragma unroll 2
        for (int hh = 0; hh < 8; ++hh) {
            const int* si = sel_idx + ((size_t)b * H + h0 + hh) * 3;
            const int g0 = si[0] * 3, g1 = si[1] * 3, g2 = si[2] * 3;
            const float p0x = sm.p2.gp[g0],     p0y = sm.p2.gp[g0 + 1], p0z = sm.p2.gp[g0 + 2];
            const float p1x = sm.p2.gp[g1],     p1y = sm.p2.gp[g1 + 1], p1z = sm.p2.gp[g1 + 2];
            const float p2x = sm.p2.gp[g2],     p2y = sm.p2.gp[g2 + 1], p2z = sm.p2.gp[g2 + 2];
            const float e1x = p1x - p0x, e1y = p1y - p0y, e1z = p1z - p0z;
            const float e2x = p2x - p0x, e2y = p2y - p0y, e2z = p2z - p0z;
            float x = e1y * e2z - e1z * e2y;
            float y = e1z * e2x - e1x * e2z;
            float z = e1x * e2y - e1y * e2x;
            float d = -(x * p0x + y * p0y + z * p0z);
            if (x == 0.f && y == 0.f && z == 0.f && d == 0.f) { x = y = z = d = 1.f; }
            const float ns = S_SCALE / sqrtf(x * x + y * y + z * z);
            nx[hh] = x * ns; ny[hh] = y * ns; nz[hh] = z * ns; pd[hh] = d * ns;
            acc[hh] = 0.f;
        }

        #pragma unroll 4
        for (int k = 0; k < N / 64; ++k) {
            const int n = lane + (k << 6);
            const float px = sm.p2.sp[n], py = sm.p2.sp[N + n], pz = sm.p2.sp[2 * N + n];
            #pragma unroll
            for (int hh = 0; hh < 8; ++hh) {
                const float u = fmaf(nx[hh], px, fmaf(ny[hh], py, fmaf(nz[hh], pz, pd[hh])));
                acc[hh] += exp2_fast(-(u * u));  // neg folds into v_exp src modifier
            }
        }

        const float tx = target[b * 3 + 0], ty = target[b * 3 + 1], tz = target[b * 3 + 2];
        #pragma unroll
        for (int hh = 0; hh < 8; ++hh) {
            float a = acc[hh];
            #pragma unroll
            for (int off = 32; off; off >>= 1) a += __shfl_xor(a, off);
            if (lane == 0) {
                const float x = nx[hh] * INV_S, y = ny[hh] * INV_S, z = nz[hh] * INV_S;
                const float l1 = (x - tx) * (x - tx) + (y - ty) * (y - ty) + (z - tz) * (z - tz);
                const float l2 = (x + tx) * (x + tx) + (y + ty) * (y + ty) + (z + tz) * (z + tz);
                const int idx = b * H + h0 + hh;
                score[idx] = a;
                loss[idx] = fminf(l1, l2);
                normals[idx * 3 + 0] = x;
                normals[idx * 3 + 1] = y;
                normals[idx * 3 + 2] = z;
            }
        }
    }

    // ---------------- phase 3: last block per batch finalizes ----------------
    __threadfence();
    __syncthreads();
    if (tid == 0) s_last = (atomicAdd(&cnt[b], 1) == 15);
    __syncthreads();
    if (!s_last) return;
    __threadfence();

    {
        const float* sc = score + b * H;
        const float* ls = loss + b * H;
        const float s0 = sc[tid], s1 = sc[tid + 256];

        float v; int vi;
        if (s1 > s0) { v = s1; vi = tid + 256; } else { v = s0; vi = tid; }
        #pragma unroll
        for (int off = 32; off; off >>= 1) {
            const float v2 = __shfl_xor(v, off);
            const int i2 = __shfl_xor(vi, off);
            if (v2 > v || (v2 == v && i2 < vi)) { v = v2; vi = i2; }
        }
        if (lane == 0) { sm.p3.v[wave] = v; sm.p3.idx[wave] = vi; }
        __syncthreads();
        if (tid == 0) {
            float bv = sm.p3.v[0]; int bi = sm.p3.idx[0];
            #pragma unroll
            for (int k = 1; k < 4; ++k) {
                if (sm.p3.v[k] > bv || (sm.p3.v[k] == bv && sm.p3.idx[k] < bi)) {
                    bv = sm.p3.v[k]; bi = sm.p3.idx[k];
                }
            }
            sm.p3.smax = bv; sm.p3.smaxi = bi;
        }
        __syncthreads();
        const float m = sm.p3.smax;
        const float w0 = __expf(0.5f * (s0 - m)), w1 = __expf(0.5f * (s1 - m));
        float tw = w0 + w1;
        float twl = w0 * ls[tid] + w1 * ls[tid + 256];
        #pragma unroll
        for (int off = 32; off; off >>= 1) {
            tw += __shfl_xor(tw, off);
            twl += __shfl_xor(twl, off);
        }
        if (lane == 0) { sm.p3.sw[wave] = tw; sm.p3.swl[wave] = twl; }
        __syncthreads();
        if (tid == 0) {
            const float TW = sm.p3.sw[0] + sm.p3.sw[1] + sm.p3.sw[2] + sm.p3.sw[3];
            const float TWL = sm.p3.swl[0] + sm.p3.swl[1] + sm.p3.swl[2] + sm.p3.swl[3];
            const int mi = sm.p3.smaxi;
            out[b] = TWL / TW;                               // exp_loss
            out[B + b] = ls[mi];                             // top_loss
            out[2 * B + b * 3 + 0] = normals[((size_t)b * H + mi) * 3 + 0];
            out[2 * B + b * 3 + 1] = normals[((size_t)b * H + mi) * 3 + 1];
            out[2 * B + b * 3 + 2] = normals[((size_t)b * H + mi) * 3 + 2];
        }
    }
}

// ---------------------------------------------------------------------------
extern "C" void kernel_launch(void* const* d_in, const int* in_sizes, int n_in,
                              void* d_out, int out_size, void* d_ws, size_t ws_size,
                              hipStream_t stream) {
    const float* pts       = (const float*)d_in[0];
    const float* target    = (const float*)d_in[1];
    const float* pt_weight = (const float*)d_in[2];
    const int*   sel_idx   = (const int*)d_in[3];

    float* out = (float*)d_out;
    float* ws = (float*)d_ws;
    float* score   = ws;                  // B*H
    float* loss    = ws + B * H;          // B*H
    float* normals = ws + 2 * B * H;      // B*H*3
    int*   cnt     = (int*)(ws + 5 * B * H);  // B

    int mode = 0;
    void* args[] = { (void*)&pts, (void*)&target, (void*)&pt_weight, (void*)&sel_idx,
                     (void*)&out, (void*)&score, (void*)&loss, (void*)&normals,
                     (void*)&cnt, (void*)&mode };
    hipError_t err = hipLaunchCooperativeKernel((const void*)wdsac_kernel,
                                                dim3(NBLK), dim3(NTHR), args, 0, stream);
    if (err != hipSuccess) {
        // fallback: same kernel as two ordinary launches (kernel boundary = sync)
        wdsac_kernel<<<NBLK, NTHR, 0, stream>>>(pts, target, pt_weight, sel_idx,
                                                out, score, loss, normals, cnt, 1);
        wdsac_kernel<<<NBLK, NTHR, 0, stream>>>(pts, target, pt_weight, sel_idx,
                                                out, score, loss, normals, cnt, 2);
    }
}

// Round 4
// 150.799 us; speedup vs baseline: 1.5846x; 1.5846x over previous
//
#include <hip/hip_runtime.h>

#define B 64
#define N 1024
#define G 256
#define H 512

// exp(-50*d^2) = 2^(-72.134752*d^2); pre-scale plane coeffs by sqrt(72.134752)
#define S_SCALE 8.4932183f
#define INV_S   (1.0f / S_SCALE)

__device__ __forceinline__ float exp2_fast(float x) {
#if __has_builtin(__builtin_amdgcn_exp2f)
    return __builtin_amdgcn_exp2f(x);   // raw v_exp_f32
#else
    return __expf(x * 0.69314718056f);  // e^(x ln2) = 2^x
#endif
}

// ---------------------------------------------------------------------------
// Kernel 1: stable top-k (k=G=256) of pt_weight per batch via O(N^2) ranking.
// 4 blocks per batch (256 threads each); thread ranks one element against all
// N via broadcast float4 LDS reads.
// rank_i = #{ j : w_j > w_i  or (w_j == w_i and j < i) }  -> exact lax.top_k
// order (descending value, ties broken by lower index). Also zeroes the
// per-batch finalize counter for kernel 2.
// ---------------------------------------------------------------------------
#define TKB 4  // blocks per batch

__global__ __launch_bounds__(256) void topk_gather_kernel(
    const float* __restrict__ pts,        // (B,3,N)
    const float* __restrict__ pt_weight,  // (B,N)
    float* __restrict__ out_gpts,         // (B,G,3)
    int* __restrict__ cnt)                // (B) finalize counters, zeroed here
{
    const int b = blockIdx.x / TKB;
    const int q = blockIdx.x % TKB;

    __shared__ float w[N];
    ((float4*)w)[threadIdx.x] = ((const float4*)(pt_weight + (size_t)b * N))[threadIdx.x];
    if (q == 0 && threadIdx.x == 0) cnt[b] = 0;
    __syncthreads();

    const int i = q * 256 + threadIdx.x;
    const float wi = w[i];

    int rank = 0;
#pragma unroll 8
    for (int j = 0; j < N; j += 4) {
        const float4 wj = *(const float4*)(w + j);  // broadcast LDS read
        rank += (wj.x > wi) || (wj.x == wi && (j + 0) < i);
        rank += (wj.y > wi) || (wj.y == wi && (j + 1) < i);
        rank += (wj.z > wi) || (wj.z == wi && (j + 2) < i);
        rank += (wj.w > wi) || (wj.w == wi && (j + 3) < i);
    }

    if (rank < G) {
        float* dst = out_gpts + ((size_t)b * G + rank) * 3;
        dst[0] = pts[b * 3 * N + 0 * N + i];
        dst[1] = pts[b * 3 * N + 1 * N + i];
        dst[2] = pts[b * 3 * N + 2 * N + i];
    }
}

// ---------------------------------------------------------------------------
// Kernel 2: plane + score + loss, then last-block-per-batch finalize (argmax,
// softmax, exp_loss, top_loss, pred) — no grid sync needed: the last block of
// each batch (detected by device-scope atomic counter) does the reduction.
// One block = one batch x 32 hypotheses; pts[b] (12KB) + gpts[b] (3KB) in LDS.
// Each wave evaluates its 8 hypotheses per point-load (LDS reads amortized).
// ---------------------------------------------------------------------------
union SMem {
    struct { float sp[3 * N]; float gp[3 * G]; } p2;      // 15.4 KB
    struct { float v[4]; int idx[4]; float sw[4]; float swl[4];
             float smax; int smaxi; } p3;
};

__global__ __launch_bounds__(256) void plane_finalize_kernel(
    const float* __restrict__ pts,      // (B,3,N)
    const float* __restrict__ target,   // (B,3)
    const int* __restrict__ sel_idx,    // (B,H,3)
    float* __restrict__ out,            // exp_loss(B)|top_loss(B)|pred(3B)|gpts(B,G,3)
    float* __restrict__ score,          // ws (B,H)
    float* __restrict__ loss,           // ws (B,H)
    float* __restrict__ normals,        // ws (B,H,3)
    int* __restrict__ cnt)              // ws (B)
{
    __shared__ SMem sm;
    __shared__ bool s_last;
    const int blk = blockIdx.x;
    const int tid = threadIdx.x;
    const int b   = blk >> 4;   // 64 batches
    const int hg  = blk & 15;   // 16 hypothesis-groups per batch
    const int wave = tid >> 6;
    const int lane = tid & 63;
    const float* gpts = out + 5 * B;  // gathered points written by kernel 1

    // ---------------- stage pts + gpts into LDS ----------------
    {
        const float4* ps = (const float4*)(pts + (size_t)b * 3 * N);
        float4* spv = (float4*)sm.p2.sp;
        spv[tid]       = ps[tid];
        spv[tid + 256] = ps[tid + 256];
        spv[tid + 512] = ps[tid + 512];
        if (tid < 192)
            ((float4*)sm.p2.gp)[tid] =
                ((const float4*)(gpts + (size_t)b * 3 * G))[tid];
    }
    __syncthreads();

    // ---------------- plane + score + loss ----------------
    {
        const int h0 = (hg << 5) + (wave << 3);  // 32 hyps/block, 8/wave
        float nx[8], ny[8], nz[8], pd[8], acc[8];

        #pragma unroll 2
        for (int hh = 0; hh < 8; ++hh) {
            const int* si = sel_idx + ((size_t)b * H + h0 + hh) * 3;
            const int g0 = si[0] * 3, g1 = si[1] * 3, g2 = si[2] * 3;
            const float p0x = sm.p2.gp[g0], p0y = sm.p2.gp[g0 + 1], p0z = sm.p2.gp[g0 + 2];
            const float p1x = sm.p2.gp[g1], p1y = sm.p2.gp[g1 + 1], p1z = sm.p2.gp[g1 + 2];
            const float p2x = sm.p2.gp[g2], p2y = sm.p2.gp[g2 + 1], p2z = sm.p2.gp[g2 + 2];
            const float e1x = p1x - p0x, e1y = p1y - p0y, e1z = p1z - p0z;
            const float e2x = p2x - p0x, e2y = p2y - p0y, e2z = p2z - p0z;
            float x = e1y * e2z - e1z * e2y;
            float y = e1z * e2x - e1x * e2z;
            float z = e1x * e2y - e1y * e2x;
            float d = -(x * p0x + y * p0y + z * p0z);
            if (x == 0.f && y == 0.f && z == 0.f && d == 0.f) { x = y = z = d = 1.f; }
            const float ns = S_SCALE / sqrtf(x * x + y * y + z * z);
            nx[hh] = x * ns; ny[hh] = y * ns; nz[hh] = z * ns; pd[hh] = d * ns;
            acc[hh] = 0.f;
        }

        #pragma unroll 4
        for (int k = 0; k < N / 64; ++k) {
            const int n = lane + (k << 6);
            const float px = sm.p2.sp[n], py = sm.p2.sp[N + n], pz = sm.p2.sp[2 * N + n];
            #pragma unroll
            for (int hh = 0; hh < 8; ++hh) {
                const float u = fmaf(nx[hh], px, fmaf(ny[hh], py, fmaf(nz[hh], pz, pd[hh])));
                acc[hh] += exp2_fast(-(u * u));  // neg folds into v_exp src modifier
            }
        }

        const float tx = target[b * 3 + 0], ty = target[b * 3 + 1], tz = target[b * 3 + 2];
        #pragma unroll
        for (int hh = 0; hh < 8; ++hh) {
            float a = acc[hh];
            #pragma unroll
            for (int off = 32; off; off >>= 1) a += __shfl_xor(a, off);
            if (lane == 0) {
                const float x = nx[hh] * INV_S, y = ny[hh] * INV_S, z = nz[hh] * INV_S;
                const float l1 = (x - tx) * (x - tx) + (y - ty) * (y - ty) + (z - tz) * (z - tz);
                const float l2 = (x + tx) * (x + tx) + (y + ty) * (y + ty) + (z + tz) * (z + tz);
                const int idx = b * H + h0 + hh;
                score[idx] = a;
                loss[idx] = fminf(l1, l2);
                normals[idx * 3 + 0] = x;
                normals[idx * 3 + 1] = y;
                normals[idx * 3 + 2] = z;
            }
        }
    }

    // ---------------- last block of batch b finalizes ----------------
    __threadfence();           // release: publish score/loss/normals
    __syncthreads();
    if (tid == 0) s_last = (atomicAdd(&cnt[b], 1) == 15);
    __syncthreads();
    if (!s_last) return;
    __threadfence();           // acquire: see all 16 blocks' writes

    {
        const float* sc = score + b * H;
        const float* ls = loss + b * H;
        const float s0 = sc[tid], s1 = sc[tid + 256];

        float v; int vi;
        if (s1 > s0) { v = s1; vi = tid + 256; } else { v = s0; vi = tid; }
        #pragma unroll
        for (int off = 32; off; off >>= 1) {
            const float v2 = __shfl_xor(v, off);
            const int i2 = __shfl_xor(vi, off);
            if (v2 > v || (v2 == v && i2 < vi)) { v = v2; vi = i2; }
        }
        if (lane == 0) { sm.p3.v[wave] = v; sm.p3.idx[wave] = vi; }
        __syncthreads();
        if (tid == 0) {
            float bv = sm.p3.v[0]; int bi = sm.p3.idx[0];
            #pragma unroll
            for (int k = 1; k < 4; ++k) {
                if (sm.p3.v[k] > bv || (sm.p3.v[k] == bv && sm.p3.idx[k] < bi)) {
                    bv = sm.p3.v[k]; bi = sm.p3.idx[k];
                }
            }
            sm.p3.smax = bv; sm.p3.smaxi = bi;
        }
        __syncthreads();
        const float m = sm.p3.smax;
        const float w0 = __expf(0.5f * (s0 - m)), w1 = __expf(0.5f * (s1 - m));
        float tw = w0 + w1;
        float twl = w0 * ls[tid] + w1 * ls[tid + 256];
        #pragma unroll
        for (int off = 32; off; off >>= 1) {
            tw += __shfl_xor(tw, off);
            twl += __shfl_xor(twl, off);
        }
        if (lane == 0) { sm.p3.sw[wave] = tw; sm.p3.swl[wave] = twl; }
        __syncthreads();
        if (tid == 0) {
            const float TW = sm.p3.sw[0] + sm.p3.sw[1] + sm.p3.sw[2] + sm.p3.sw[3];
            const float TWL = sm.p3.swl[0] + sm.p3.swl[1] + sm.p3.swl[2] + sm.p3.swl[3];
            const int mi = sm.p3.smaxi;
            out[b] = TWL / TW;                               // exp_loss
            out[B + b] = ls[mi];                             // top_loss
            out[2 * B + b * 3 + 0] = normals[((size_t)b * H + mi) * 3 + 0];
            out[2 * B + b * 3 + 1] = normals[((size_t)b * H + mi) * 3 + 1];
            out[2 * B + b * 3 + 2] = normals[((size_t)b * H + mi) * 3 + 2];
        }
    }
}

// ---------------------------------------------------------------------------
extern "C" void kernel_launch(void* const* d_in, const int* in_sizes, int n_in,
                              void* d_out, int out_size, void* d_ws, size_t ws_size,
                              hipStream_t stream) {
    const float* pts       = (const float*)d_in[0];  // (B,3,N)
    const float* target    = (const float*)d_in[1];  // (B,3)
    const float* pt_weight = (const float*)d_in[2];  // (B,N)
    const int*   sel_idx   = (const int*)d_in[3];    // (B,H,3)

    float* out = (float*)d_out;
    // layout: exp_loss[B] | top_loss[B] | pred[B*3] | gpts[B*G*3]
    float* out_gpts = out + 5 * B;

    float* ws      = (float*)d_ws;
    float* score   = ws;                      // B*H
    float* loss    = ws + B * H;              // B*H
    float* normals = ws + 2 * B * H;          // B*H*3
    int*   cnt     = (int*)(ws + 5 * B * H);  // B

    topk_gather_kernel<<<B * TKB, 256, 0, stream>>>(pts, pt_weight, out_gpts, cnt);
    plane_finalize_kernel<<<B * 16, 256, 0, stream>>>(pts, target, sel_idx, out,
                                                      score, loss, normals, cnt);
}